// Round 1
// baseline (1102.151 us; speedup 1.0000x reference)
//
#include <hip/hip_runtime.h>

typedef _Float16 f16;
typedef _Float16 f16x8 __attribute__((ext_vector_type(8)));
typedef float f32x4 __attribute__((ext_vector_type(4)));

#define TILE 128
#define BK 32

__device__ __forceinline__ void async_cp16(const void* g, void* l) {
  __builtin_amdgcn_global_load_lds(
      (const __attribute__((address_space(1))) void*)g,
      (__attribute__((address_space(3))) void*)l, 16, 0, 0);
}

// C = A @ Bt^T where A is [M][K] f16 row-major, Bt is [N][K] f16 row-major.
// EPI 0: C = f16(relu(acc + bias[col]))   (layer 0)
// EPI 1: C = f16(acc)                      (pre-LN layers)
template <int EPI>
__global__ __launch_bounds__(256) void gemm_f16(
    const f16* __restrict__ A, const f16* __restrict__ Bt,
    const float* __restrict__ bias, f16* __restrict__ C,
    int M, int N, int K) {
  __shared__ alignas(16) f16 sA[TILE][BK];
  __shared__ alignas(16) f16 sB[TILE][BK];
  const int tid = threadIdx.x;
  const int lane = tid & 63;
  const int wave = tid >> 6;
  const long long bm = (long long)blockIdx.y * TILE;
  const long long bn = (long long)blockIdx.x * TILE;
  const int wm = (wave & 1) * 64;   // wave's row band within tile
  const int wn = (wave >> 1) * 64;  // wave's col band within tile
  const int r15 = lane & 15;
  const int quad = lane >> 4;

  f32x4 acc[4][4] = {};  // 4x4 tiles of 16x16, rows = i, cols = j

  const int kIters = K / BK;
  for (int kt = 0; kt < kIters; ++kt) {
    const int k0 = kt * BK;
    // Stage A and Bt tiles: 512 chunks of 16B each per tile; each wave covers
    // 128 chunks (2 insts). chunk = ml*4 + kc maps to LDS offset chunk*16B
    // (contiguous, matching wave-uniform base + lane*16 semantics).
#pragma unroll
    for (int i = 0; i < 2; ++i) {
      const int chunk = wave * 128 + i * 64 + lane;
      const int ml = chunk >> 2;
      const int kc = chunk & 3;
      async_cp16(A + (bm + ml) * (long long)K + k0 + kc * 8,
                 &sA[0][0] + (long long)(wave * 128 + i * 64) * 8);
      async_cp16(Bt + (bn + ml) * (long long)K + k0 + kc * 8,
                 &sB[0][0] + (long long)(wave * 128 + i * 64) * 8);
    }
    __syncthreads();

    f16x8 af[4], bf[4];
#pragma unroll
    for (int i = 0; i < 4; ++i) {
      af[i] = *(const f16x8*)&sA[wm + i * 16 + r15][quad * 8];
      bf[i] = *(const f16x8*)&sB[wn + i * 16 + r15][quad * 8];
    }
#pragma unroll
    for (int i = 0; i < 4; ++i)
#pragma unroll
      for (int j = 0; j < 4; ++j)
        acc[i][j] =
            __builtin_amdgcn_mfma_f32_16x16x32_f16(af[i], bf[j], acc[i][j], 0, 0, 0);
    __syncthreads();
  }

  // Epilogue. D mapping: row = quad*4 + r, col = lane&15 (verified m89/m91).
#pragma unroll
  for (int j = 0; j < 4; ++j) {
    const long long colg = bn + wn + j * 16 + r15;
    float bval = 0.f;
    if (EPI == 0) bval = bias[colg];
#pragma unroll
    for (int i = 0; i < 4; ++i) {
#pragma unroll
      for (int r = 0; r < 4; ++r) {
        const long long rowg = bm + wm + i * 16 + quad * 4 + r;
        float v = acc[i][j][r];
        if (EPI == 0) v = fmaxf(v + bval, 0.f);
        C[rowg * N + colg] = (f16)v;
      }
    }
  }
}

// One wave per row: LayerNorm(y) * g + b, relu, write f16.
__global__ __launch_bounds__(256) void ln_relu_kernel(
    const f16* __restrict__ Y, const float* __restrict__ g,
    const float* __restrict__ b, f16* __restrict__ H) {
  const int lane = threadIdx.x & 63;
  const int wave = threadIdx.x >> 6;
  const long long row = (long long)blockIdx.x * 4 + wave;
  const f16* y = Y + row * 1024;
  float x[16];
  float s1 = 0.f, s2 = 0.f;
#pragma unroll
  for (int p = 0; p < 2; ++p) {
    f16x8 v = *(const f16x8*)(y + p * 512 + lane * 8);
#pragma unroll
    for (int e = 0; e < 8; ++e) {
      const float f = (float)v[e];
      x[p * 8 + e] = f;
      s1 += f;
      s2 += f * f;
    }
  }
#pragma unroll
  for (int off = 32; off >= 1; off >>= 1) {
    s1 += __shfl_xor(s1, off);
    s2 += __shfl_xor(s2, off);
  }
  const float mean = s1 * (1.f / 1024.f);
  const float var = fmaxf(s2 * (1.f / 1024.f) - mean * mean, 0.f);
  const float inv = rsqrtf(var + 1e-6f);
  f16* h = H + row * 1024;
#pragma unroll
  for (int p = 0; p < 2; ++p) {
    f16x8 o;
#pragma unroll
    for (int e = 0; e < 8; ++e) {
      const int c = p * 512 + lane * 8 + e;
      const float v = (x[p * 8 + e] - mean) * inv * g[c] + b[c];
      o[e] = (f16)fmaxf(v, 0.f);
    }
    *(f16x8*)(h + p * 512 + lane * 8) = o;
  }
}

// One wave per row: out[row] = relu(dot(h[row], Wout) + bout)
__global__ __launch_bounds__(256) void out_kernel(
    const f16* __restrict__ H, const float* __restrict__ Wout,
    const float* __restrict__ bout, float* __restrict__ out) {
  const int lane = threadIdx.x & 63;
  const int wave = threadIdx.x >> 6;
  const long long row = (long long)blockIdx.x * 4 + wave;
  const f16* h = H + row * 1024;
  float s = 0.f;
#pragma unroll
  for (int p = 0; p < 2; ++p) {
    f16x8 v = *(const f16x8*)(h + p * 512 + lane * 8);
#pragma unroll
    for (int e = 0; e < 8; ++e) s += (float)v[e] * Wout[p * 512 + lane * 8 + e];
  }
#pragma unroll
  for (int off = 32; off >= 1; off >>= 1) s += __shfl_xor(s, off);
  if (lane == 0) out[row] = fmaxf(s + bout[0], 0.f);
}

// fp32 -> f16 elementwise (8 per thread)
__global__ __launch_bounds__(256) void cvt_f16_kernel(const float* __restrict__ X,
                                                      f16* __restrict__ Y,
                                                      long long n) {
  const long long i = ((long long)blockIdx.x * 256 + threadIdx.x) * 8;
  if (i >= n) return;
  const float4* X4 = (const float4*)(X + i);
  const float4 a = X4[0], c = X4[1];
  f16x8 o;
  o[0] = (f16)a.x; o[1] = (f16)a.y; o[2] = (f16)a.z; o[3] = (f16)a.w;
  o[4] = (f16)c.x; o[5] = (f16)c.y; o[6] = (f16)c.z; o[7] = (f16)c.w;
  *(f16x8*)(Y + i) = o;
}

// W [K][N] fp32 -> Wt [N][K] f16, 64x64 LDS tiles
__global__ __launch_bounds__(256) void transpose_cvt(const float* __restrict__ W,
                                                     f16* __restrict__ Wt, int K,
                                                     int N) {
  __shared__ float tile[64][65];
  const int bn = blockIdx.x * 64;
  const int bk = blockIdx.y * 64;
  const int tx = threadIdx.x & 63;
  const int ty = threadIdx.x >> 6;  // 0..3
#pragma unroll
  for (int i = 0; i < 64; i += 4)
    tile[ty + i][tx] = W[(long long)(bk + ty + i) * N + bn + tx];
  __syncthreads();
#pragma unroll
  for (int i = 0; i < 64; i += 4)
    Wt[(long long)(bn + ty + i) * K + bk + tx] = (f16)tile[tx][ty + i];
}

extern "C" void kernel_launch(void* const* d_in, const int* in_sizes, int n_in,
                              void* d_out, int out_size, void* d_ws, size_t ws_size,
                              hipStream_t stream) {
  const float* desc = (const float*)d_in[0];
  const float* W0 = (const float*)d_in[1];
  const float* b0 = (const float*)d_in[2];
  const float* W1 = (const float*)d_in[3];
  const float* g1 = (const float*)d_in[4];
  const float* be1 = (const float*)d_in[5];
  const float* W2 = (const float*)d_in[6];
  const float* g2 = (const float*)d_in[7];
  const float* be2 = (const float*)d_in[8];
  const float* W3 = (const float*)d_in[9];
  const float* g3 = (const float*)d_in[10];
  const float* be3 = (const float*)d_in[11];
  const float* Wout = (const float*)d_in[12];
  const float* bout = (const float*)d_in[13];
  float* out = (float*)d_out;

  const long long Nrows = 65536, D = 512, W = 1024;
  char* p = (char*)d_ws;
  f16* descH = (f16*)p; p += Nrows * D * sizeof(f16);   // 67.1 MB
  f16* Wt0 = (f16*)p;   p += D * W * sizeof(f16);       // 1 MB
  f16* Wt1 = (f16*)p;   p += W * W * sizeof(f16);       // 2 MB
  f16* Wt2 = (f16*)p;   p += W * W * sizeof(f16);       // 2 MB
  f16* Wt3 = (f16*)p;   p += W * W * sizeof(f16);       // 2 MB
  f16* H = (f16*)p;     p += Nrows * W * sizeof(f16);   // 134.2 MB
  f16* Y = (f16*)p;     p += Nrows * W * sizeof(f16);   // 134.2 MB
  (void)ws_size; (void)in_sizes; (void)n_in; (void)out_size;

  cvt_f16_kernel<<<(int)(Nrows * D / 8 / 256), 256, 0, stream>>>(desc, descH,
                                                                 Nrows * D);
  transpose_cvt<<<dim3(W / 64, D / 64), 256, 0, stream>>>(W0, Wt0, (int)D, (int)W);
  transpose_cvt<<<dim3(W / 64, W / 64), 256, 0, stream>>>(W1, Wt1, (int)W, (int)W);
  transpose_cvt<<<dim3(W / 64, W / 64), 256, 0, stream>>>(W2, Wt2, (int)W, (int)W);
  transpose_cvt<<<dim3(W / 64, W / 64), 256, 0, stream>>>(W3, Wt3, (int)W, (int)W);

  dim3 ggrid(W / TILE, Nrows / TILE);  // (8, 512)
  gemm_f16<0><<<ggrid, 256, 0, stream>>>(descH, Wt0, b0, H, (int)Nrows, (int)W, (int)D);

  gemm_f16<1><<<ggrid, 256, 0, stream>>>(H, Wt1, nullptr, Y, (int)Nrows, (int)W, (int)W);
  ln_relu_kernel<<<(int)(Nrows / 4), 256, 0, stream>>>(Y, g1, be1, H);

  gemm_f16<1><<<ggrid, 256, 0, stream>>>(H, Wt2, nullptr, Y, (int)Nrows, (int)W, (int)W);
  ln_relu_kernel<<<(int)(Nrows / 4), 256, 0, stream>>>(Y, g2, be2, H);

  gemm_f16<1><<<ggrid, 256, 0, stream>>>(H, Wt3, nullptr, Y, (int)Nrows, (int)W, (int)W);
  ln_relu_kernel<<<(int)(Nrows / 4), 256, 0, stream>>>(Y, g3, be3, H);

  out_kernel<<<(int)(Nrows / 4), 256, 0, stream>>>(H, Wout, bout, out);
}

// Round 2
// 1046.072 us; speedup vs baseline: 1.0536x; 1.0536x over previous
//
#include <hip/hip_runtime.h>

typedef _Float16 f16;
typedef _Float16 f16x8 __attribute__((ext_vector_type(8)));
typedef float f32x4 __attribute__((ext_vector_type(4)));

#define TILE 128
#define BK 32

__device__ __forceinline__ void async_cp16(const void* g, void* l) {
  __builtin_amdgcn_global_load_lds(
      (const __attribute__((address_space(1))) void*)g,
      (__attribute__((address_space(3))) void*)l, 16, 0, 0);
}

// C = A @ Bt^T where A is [M][K] f16 row-major, Bt is [N][K] f16 row-major.
// EPI 0: C = f16(relu(acc + bias[col]))   (layer 0)
// EPI 1: C = f16(acc)                      (pre-LN layers)
// LDS layout is XOR-swizzled: tile row ml stores k-chunk kc at slot
// kc ^ ((ml>>1)&3) so that ds_read_b128 of column-of-rows covers all 8
// 16B bank groups (2-way residual aliasing = free; was 8-way = 2.94x).
template <int EPI>
__global__ __launch_bounds__(256) void gemm_f16(
    const f16* __restrict__ A, const f16* __restrict__ Bt,
    const float* __restrict__ bias, f16* __restrict__ C,
    int M, int N, int K) {
  __shared__ alignas(16) f16 sA[TILE][BK];
  __shared__ alignas(16) f16 sB[TILE][BK];
  const int tid = threadIdx.x;
  const int lane = tid & 63;
  const int wave = tid >> 6;

  // XCD-aware remap: grid is (8, 512) = 4096 blocks. Blocks sharing an
  // A-panel (same mt, nt=0..7) get ids spaced 8 apart -> same XCD under
  // round-robin dispatch, adjacent in that XCD's queue -> A panel (256 KB)
  // stays in its 4 MB L2. Identity fallback if grid differs.
  int mt, nt;
  if (gridDim.x == 8 && gridDim.y == 512) {
    const int id = blockIdx.y * 8 + blockIdx.x;
    nt = (id >> 3) & 7;
    mt = (id & 7) * 64 + (id >> 6);
  } else {
    nt = blockIdx.x;
    mt = blockIdx.y;
  }
  const long long bm = (long long)mt * TILE;
  const long long bn = (long long)nt * TILE;

  const int wm = (wave & 1) * 64;   // wave's row band within tile
  const int wn = (wave >> 1) * 64;  // wave's col band within tile
  const int r15 = lane & 15;
  const int quad = lane >> 4;
  const int qsw = ((r15 >> 1) & 3);  // read-side swizzle, i-invariant

  f32x4 acc[4][4] = {};  // 4x4 tiles of 16x16, rows = i, cols = j

  const int kIters = K / BK;
  for (int kt = 0; kt < kIters; ++kt) {
    const int k0 = kt * BK;
    // Stage A and Bt tiles: 512 chunks of 16B each per tile; LDS dest is
    // contiguous chunk*16B (wave-uniform base + lane*16). Global source
    // k-chunk is XOR-swizzled per row; 4 consecutive lanes still cover one
    // contiguous 64B row segment (permuted) -> coalescing preserved.
#pragma unroll
    for (int i = 0; i < 2; ++i) {
      const int chunk = wave * 128 + i * 64 + lane;
      const int ml = chunk >> 2;
      const int kc = (chunk & 3) ^ ((ml >> 1) & 3);
      async_cp16(A + (bm + ml) * (long long)K + k0 + kc * 8,
                 &sA[0][0] + (long long)(wave * 128 + i * 64) * 8);
      async_cp16(Bt + (bn + ml) * (long long)K + k0 + kc * 8,
                 &sB[0][0] + (long long)(wave * 128 + i * 64) * 8);
    }
    __syncthreads();

    f16x8 af[4], bf[4];
#pragma unroll
    for (int i = 0; i < 4; ++i) {
      af[i] = *(const f16x8*)&sA[wm + i * 16 + r15][(quad ^ qsw) * 8];
      bf[i] = *(const f16x8*)&sB[wn + i * 16 + r15][(quad ^ qsw) * 8];
    }
#pragma unroll
    for (int i = 0; i < 4; ++i)
#pragma unroll
      for (int j = 0; j < 4; ++j)
        acc[i][j] =
            __builtin_amdgcn_mfma_f32_16x16x32_f16(af[i], bf[j], acc[i][j], 0, 0, 0);
    __syncthreads();
  }

  // Epilogue. D mapping: row = quad*4 + r, col = lane&15 (verified m89/m91).
#pragma unroll
  for (int j = 0; j < 4; ++j) {
    const long long colg = bn + wn + j * 16 + r15;
    float bval = 0.f;
    if (EPI == 0) bval = bias[colg];
#pragma unroll
    for (int i = 0; i < 4; ++i) {
#pragma unroll
      for (int r = 0; r < 4; ++r) {
        const long long rowg = bm + wm + i * 16 + quad * 4 + r;
        float v = acc[i][j][r];
        if (EPI == 0) v = fmaxf(v + bval, 0.f);
        C[rowg * N + colg] = (f16)v;
      }
    }
  }
}

// One wave per row: LayerNorm(y) * g + b, relu, write f16.
__global__ __launch_bounds__(256) void ln_relu_kernel(
    const f16* __restrict__ Y, const float* __restrict__ g,
    const float* __restrict__ b, f16* __restrict__ H) {
  const int lane = threadIdx.x & 63;
  const int wave = threadIdx.x >> 6;
  const long long row = (long long)blockIdx.x * 4 + wave;
  const f16* y = Y + row * 1024;
  float x[16];
  float s1 = 0.f, s2 = 0.f;
#pragma unroll
  for (int p = 0; p < 2; ++p) {
    f16x8 v = *(const f16x8*)(y + p * 512 + lane * 8);
#pragma unroll
    for (int e = 0; e < 8; ++e) {
      const float f = (float)v[e];
      x[p * 8 + e] = f;
      s1 += f;
      s2 += f * f;
    }
  }
#pragma unroll
  for (int off = 32; off >= 1; off >>= 1) {
    s1 += __shfl_xor(s1, off);
    s2 += __shfl_xor(s2, off);
  }
  const float mean = s1 * (1.f / 1024.f);
  const float var = fmaxf(s2 * (1.f / 1024.f) - mean * mean, 0.f);
  const float inv = rsqrtf(var + 1e-6f);
  f16* h = H + row * 1024;
#pragma unroll
  for (int p = 0; p < 2; ++p) {
    f16x8 o;
#pragma unroll
    for (int e = 0; e < 8; ++e) {
      const int c = p * 512 + lane * 8 + e;
      const float v = (x[p * 8 + e] - mean) * inv * g[c] + b[c];
      o[e] = (f16)fmaxf(v, 0.f);
    }
    *(f16x8*)(h + p * 512 + lane * 8) = o;
  }
}

// Fused layer-3 LN + relu + output dot: out[row] = relu(dot(relu(LN(y)), Wout) + bout)
// Saves writing H (134 MB) and re-reading it (134 MB).
__global__ __launch_bounds__(256) void ln_relu_out_kernel(
    const f16* __restrict__ Y, const float* __restrict__ g,
    const float* __restrict__ b, const float* __restrict__ Wout,
    const float* __restrict__ bout, float* __restrict__ out) {
  const int lane = threadIdx.x & 63;
  const int wave = threadIdx.x >> 6;
  const long long row = (long long)blockIdx.x * 4 + wave;
  const f16* y = Y + row * 1024;
  float x[16];
  float s1 = 0.f, s2 = 0.f;
#pragma unroll
  for (int p = 0; p < 2; ++p) {
    f16x8 v = *(const f16x8*)(y + p * 512 + lane * 8);
#pragma unroll
    for (int e = 0; e < 8; ++e) {
      const float f = (float)v[e];
      x[p * 8 + e] = f;
      s1 += f;
      s2 += f * f;
    }
  }
#pragma unroll
  for (int off = 32; off >= 1; off >>= 1) {
    s1 += __shfl_xor(s1, off);
    s2 += __shfl_xor(s2, off);
  }
  const float mean = s1 * (1.f / 1024.f);
  const float var = fmaxf(s2 * (1.f / 1024.f) - mean * mean, 0.f);
  const float inv = rsqrtf(var + 1e-6f);
  float dot = 0.f;
#pragma unroll
  for (int p = 0; p < 2; ++p) {
#pragma unroll
    for (int e = 0; e < 8; ++e) {
      const int c = p * 512 + lane * 8 + e;
      const float v = fmaxf((x[p * 8 + e] - mean) * inv * g[c] + b[c], 0.f);
      dot += v * Wout[c];
    }
  }
#pragma unroll
  for (int off = 32; off >= 1; off >>= 1) dot += __shfl_xor(dot, off);
  if (lane == 0) out[row] = fmaxf(dot + bout[0], 0.f);
}

// fp32 -> f16 elementwise (8 per thread)
__global__ __launch_bounds__(256) void cvt_f16_kernel(const float* __restrict__ X,
                                                      f16* __restrict__ Y,
                                                      long long n) {
  const long long i = ((long long)blockIdx.x * 256 + threadIdx.x) * 8;
  if (i >= n) return;
  const float4* X4 = (const float4*)(X + i);
  const float4 a = X4[0], c = X4[1];
  f16x8 o;
  o[0] = (f16)a.x; o[1] = (f16)a.y; o[2] = (f16)a.z; o[3] = (f16)a.w;
  o[4] = (f16)c.x; o[5] = (f16)c.y; o[6] = (f16)c.z; o[7] = (f16)c.w;
  *(f16x8*)(Y + i) = o;
}

// W [K][N] fp32 -> Wt [N][K] f16, 64x64 LDS tiles
__global__ __launch_bounds__(256) void transpose_cvt(const float* __restrict__ W,
                                                     f16* __restrict__ Wt, int K,
                                                     int N) {
  __shared__ float tile[64][65];
  const int bn = blockIdx.x * 64;
  const int bk = blockIdx.y * 64;
  const int tx = threadIdx.x & 63;
  const int ty = threadIdx.x >> 6;  // 0..3
#pragma unroll
  for (int i = 0; i < 64; i += 4)
    tile[ty + i][tx] = W[(long long)(bk + ty + i) * N + bn + tx];
  __syncthreads();
#pragma unroll
  for (int i = 0; i < 64; i += 4)
    Wt[(long long)(bn + ty + i) * K + bk + tx] = (f16)tile[tx][ty + i];
}

extern "C" void kernel_launch(void* const* d_in, const int* in_sizes, int n_in,
                              void* d_out, int out_size, void* d_ws, size_t ws_size,
                              hipStream_t stream) {
  const float* desc = (const float*)d_in[0];
  const float* W0 = (const float*)d_in[1];
  const float* b0 = (const float*)d_in[2];
  const float* W1 = (const float*)d_in[3];
  const float* g1 = (const float*)d_in[4];
  const float* be1 = (const float*)d_in[5];
  const float* W2 = (const float*)d_in[6];
  const float* g2 = (const float*)d_in[7];
  const float* be2 = (const float*)d_in[8];
  const float* W3 = (const float*)d_in[9];
  const float* g3 = (const float*)d_in[10];
  const float* be3 = (const float*)d_in[11];
  const float* Wout = (const float*)d_in[12];
  const float* bout = (const float*)d_in[13];
  float* out = (float*)d_out;

  const long long Nrows = 65536, D = 512, W = 1024;
  char* p = (char*)d_ws;
  f16* descH = (f16*)p; p += Nrows * D * sizeof(f16);   // 67.1 MB
  f16* Wt0 = (f16*)p;   p += D * W * sizeof(f16);       // 1 MB
  f16* Wt1 = (f16*)p;   p += W * W * sizeof(f16);       // 2 MB
  f16* Wt2 = (f16*)p;   p += W * W * sizeof(f16);       // 2 MB
  f16* Wt3 = (f16*)p;   p += W * W * sizeof(f16);       // 2 MB
  f16* H = (f16*)p;     p += Nrows * W * sizeof(f16);   // 134.2 MB
  f16* Y = (f16*)p;     p += Nrows * W * sizeof(f16);   // 134.2 MB
  (void)ws_size; (void)in_sizes; (void)n_in; (void)out_size;

  cvt_f16_kernel<<<(int)(Nrows * D / 8 / 256), 256, 0, stream>>>(desc, descH,
                                                                 Nrows * D);
  transpose_cvt<<<dim3(W / 64, D / 64), 256, 0, stream>>>(W0, Wt0, (int)D, (int)W);
  transpose_cvt<<<dim3(W / 64, W / 64), 256, 0, stream>>>(W1, Wt1, (int)W, (int)W);
  transpose_cvt<<<dim3(W / 64, W / 64), 256, 0, stream>>>(W2, Wt2, (int)W, (int)W);
  transpose_cvt<<<dim3(W / 64, W / 64), 256, 0, stream>>>(W3, Wt3, (int)W, (int)W);

  dim3 ggrid(W / TILE, Nrows / TILE);  // (8, 512)
  gemm_f16<0><<<ggrid, 256, 0, stream>>>(descH, Wt0, b0, H, (int)Nrows, (int)W, (int)D);

  gemm_f16<1><<<ggrid, 256, 0, stream>>>(H, Wt1, nullptr, Y, (int)Nrows, (int)W, (int)W);
  ln_relu_kernel<<<(int)(Nrows / 4), 256, 0, stream>>>(Y, g1, be1, H);

  gemm_f16<1><<<ggrid, 256, 0, stream>>>(H, Wt2, nullptr, Y, (int)Nrows, (int)W, (int)W);
  ln_relu_kernel<<<(int)(Nrows / 4), 256, 0, stream>>>(Y, g2, be2, H);

  gemm_f16<1><<<ggrid, 256, 0, stream>>>(H, Wt3, nullptr, Y, (int)Nrows, (int)W, (int)W);
  ln_relu_out_kernel<<<(int)(Nrows / 4), 256, 0, stream>>>(Y, g3, be3, Wout, bout, out);
}